// Round 10
// baseline (562.393 us; speedup 1.0000x reference)
//
#include <hip/hip_runtime.h>
#include <hip/hip_bf16.h>

#define N_NODES 16384
#define FDIM 512

typedef __attribute__((address_space(1))) const void gvoid_t;
typedef __attribute__((address_space(3))) void lvoid_t;
typedef float vfloat4 __attribute__((ext_vector_type(4)));

#define SCHED_FENCE() __builtin_amdgcn_sched_barrier(0)

// ---------------- r9 kernel (kept for k1 = x @ W1) ----------------
template <int KTOT, int RELU, int HASBIAS>
__global__ __launch_bounds__(256, 2)
void k_rowagg(const float* __restrict__ A,
              const float* __restrict__ V,
              const float* __restrict__ bias,
              float* __restrict__ out) {
    constexpr int KT = 256;
    constexpr int NT = KTOT / KT;
    constexpr int TB = KT * 16 * 4;
    __shared__ char lv[2 * TB];

    const int tid = threadIdx.x;
    const int lane = tid & 63;
    const int w = tid >> 6;
    const size_t row0 = (size_t)blockIdx.x * 16 + (size_t)w * 4;

    int sw_src[4];
#pragma unroll
    for (int s = 0; s < 4; ++s) {
        const int D = s * 4096 + tid * 16;
        sw_src[s] = (D ^ (((D >> 8) & 7) << 4)) >> 2;
    }

    unsigned zoff = 0;

    auto STAGE = [&](int halfoff, int t) {
        const float* vt = V + (size_t)t * (KT * 16);
#pragma unroll
        for (int s = 0; s < 4; ++s) {
            __builtin_amdgcn_global_load_lds(
                (gvoid_t*)(const void*)(vt + sw_src[s]),
                (lvoid_t*)(void*)(lv + zoff + halfoff + s * 4096 + tid * 16),
                16, 0, 0);
        }
    };

    auto LOADA = [&](vfloat4 (&a)[4], int t) {
#pragma unroll
        for (int r = 0; r < 4; ++r)
            a[r] = __builtin_nontemporal_load(
                reinterpret_cast<const vfloat4*>(
                    A + (row0 + r) * (size_t)KTOT + (size_t)t * KT + lane * 4));
    };

    float acc[4][16];
#pragma unroll
    for (int r = 0; r < 4; ++r)
#pragma unroll
        for (int c = 0; c < 16; ++c) acc[r][c] = 0.f;

    auto COMPUTE = [&](const vfloat4 (&a)[4], unsigned roff) {
#pragma unroll
        for (int kk = 0; kk < 4; ++kk) {
            vfloat4 vv[4];
#pragma unroll
            for (int cc = 0; cc < 4; ++cc) {
                const unsigned B = (unsigned)lane * 256u + ((unsigned)kk << 6) +
                                   ((unsigned)cc << 4);
                const unsigned P = B ^ (((unsigned)lane & 7u) << 4);
                vv[cc] = *reinterpret_cast<const vfloat4*>(lv + roff + P);
            }
#pragma unroll
            for (int cc = 0; cc < 4; ++cc) {
#pragma unroll
                for (int r = 0; r < 4; ++r) {
                    const float ak = a[r][kk];
                    acc[r][cc * 4 + 0] += ak * vv[cc][0];
                    acc[r][cc * 4 + 1] += ak * vv[cc][1];
                    acc[r][cc * 4 + 2] += ak * vv[cc][2];
                    acc[r][cc * 4 + 3] += ak * vv[cc][3];
                }
            }
        }
    };

    vfloat4 a0[4], a1[4];

    STAGE(0, 0);
    SCHED_FENCE();
    LOADA(a0, 0);
    SCHED_FENCE();
    asm volatile("s_waitcnt vmcnt(4)" ::: "memory");
    __builtin_amdgcn_s_barrier();
    asm volatile("" : "+v"(zoff));
    SCHED_FENCE();

#pragma unroll 1
    for (int t = 0; t < NT; t += 2) {
        STAGE(TB, t + 1);
        SCHED_FENCE();
        LOADA(a1, t + 1);
        SCHED_FENCE();
        COMPUTE(a0, zoff + 0);
        SCHED_FENCE();
        asm volatile("s_waitcnt vmcnt(4)" ::: "memory");
        __builtin_amdgcn_s_barrier();
        asm volatile("" : "+v"(zoff));
        SCHED_FENCE();

        if (t + 2 < NT) {
            STAGE(0, t + 2);
            SCHED_FENCE();
            LOADA(a0, t + 2);
            SCHED_FENCE();
            COMPUTE(a1, zoff + TB);
            SCHED_FENCE();
            asm volatile("s_waitcnt vmcnt(4)" ::: "memory");
            __builtin_amdgcn_s_barrier();
            asm volatile("" : "+v"(zoff));
            SCHED_FENCE();
        } else {
            COMPUTE(a1, zoff + TB);
        }
    }

    float o = 0.f;
#pragma unroll
    for (int r = 0; r < 4; ++r) {
#pragma unroll
        for (int c = 0; c < 16; ++c) {
            float s = acc[r][c];
            s += __shfl_xor(s, 1);  s += __shfl_xor(s, 2);  s += __shfl_xor(s, 4);
            s += __shfl_xor(s, 8);  s += __shfl_xor(s, 16); s += __shfl_xor(s, 32);
            o = (r * 16 + c == lane) ? s : o;
        }
    }
    if (HASBIAS) o += bias[lane & 15];
    if (RELU) o = fmaxf(o, 0.f);
    out[row0 * 16 + lane] = o;
}

// ---------------- A-pass kernel: 2 KB contiguous row visits (activation theory) ----------------
// RPW=2 rows/wave, 4 waves/block (8 rows). Per 512-k period each row's A is read
// as TWO adjacent dwordx4 issued back-to-back -> one contiguous 2 KB DRAM visit
// (halves bank-activation rate vs r9's 1 KB; 41 ns/act vs tRC~45 was the wall).
// V staged in 256-k halves through a 3-slot 16 KB ring (48 KB LDS -> 3 blocks/CU,
// 12 waves/CU; VGPR ~107 stays in the 4-wave tier). Steps = halves (64/pass):
// step j: barrier; stage(half j+2 -> slot of j-1); [even: A-pair p+1]; vmcnt(12);
// compute(half j). vmcnt(12) retires glds(j+1) exactly; A-pair stays in flight
// across barriers. Drain (last 4 steps) uses vmcnt(0).
template <int RELU, int HASBIAS>
__global__ __launch_bounds__(256, 2)
void k_rowagg2(const float* __restrict__ A,
               const float* __restrict__ V,
               const float* __restrict__ bias,
               float* __restrict__ out) {
    constexpr int SLOT = 16384;            // 256 k x 16 c x 4 B
    __shared__ char lv[3 * SLOT];          // 48 KB ring

    const int tid = threadIdx.x;
    const int lane = tid & 63;
    const int w = tid >> 6;
    const size_t row0 = (size_t)blockIdx.x * 8 + (size_t)w * 2;

    int sw_src[4];
#pragma unroll
    for (int s = 0; s < 4; ++s) {
        const int D = s * 4096 + tid * 16;
        sw_src[s] = (D ^ (((D >> 8) & 7) << 4)) >> 2;
    }

    unsigned zoff = 0;

    auto STAGE = [&](unsigned slotoff, int h) {  // stage half h (256 k) into ring slot
        const float* vt = V + (size_t)h * 4096;
#pragma unroll
        for (int s = 0; s < 4; ++s) {
            __builtin_amdgcn_global_load_lds(
                (gvoid_t*)(const void*)(vt + sw_src[s]),
                (lvoid_t*)(void*)(lv + zoff + slotoff + s * 4096 + tid * 16),
                16, 0, 0);
        }
    };

    auto PAIR = [&](vfloat4 (&a)[2][2], int p) { // A for period p: 2 rows x 2 KB contiguous
#pragma unroll
        for (int r = 0; r < 2; ++r) {
            const float* ap = A + (row0 + r) * (size_t)N_NODES + (size_t)p * 512 + lane * 4;
            a[r][0] = __builtin_nontemporal_load(reinterpret_cast<const vfloat4*>(ap));
            a[r][1] = __builtin_nontemporal_load(reinterpret_cast<const vfloat4*>(ap + 256));
        }
    };

    float acc[2][16];
#pragma unroll
    for (int r = 0; r < 2; ++r)
#pragma unroll
        for (int c = 0; c < 16; ++c) acc[r][c] = 0.f;

    auto COMP = [&](const vfloat4& x0, const vfloat4& x1, unsigned roff) {
#pragma unroll
        for (int kk = 0; kk < 4; ++kk) {
            vfloat4 vv[4];
#pragma unroll
            for (int cc = 0; cc < 4; ++cc) {
                const unsigned B = (unsigned)lane * 256u + ((unsigned)kk << 6) +
                                   ((unsigned)cc << 4);
                const unsigned P = B ^ (((unsigned)lane & 7u) << 4);
                vv[cc] = *reinterpret_cast<const vfloat4*>(lv + zoff + roff + P);
            }
#pragma unroll
            for (int cc = 0; cc < 4; ++cc) {
                const float a0k = x0[kk], a1k = x1[kk];
                acc[0][cc * 4 + 0] += a0k * vv[cc][0];
                acc[0][cc * 4 + 1] += a0k * vv[cc][1];
                acc[0][cc * 4 + 2] += a0k * vv[cc][2];
                acc[0][cc * 4 + 3] += a0k * vv[cc][3];
                acc[1][cc * 4 + 0] += a1k * vv[cc][0];
                acc[1][cc * 4 + 1] += a1k * vv[cc][1];
                acc[1][cc * 4 + 2] += a1k * vv[cc][2];
                acc[1][cc * 4 + 3] += a1k * vv[cc][3];
            }
        }
    };

#define VMW(n) asm volatile("s_waitcnt vmcnt(" #n ")" ::: "memory")
#define BARL() do { __builtin_amdgcn_s_barrier(); \
                    asm volatile("" : "+v"(zoff)); SCHED_FENCE(); } while (0)

    vfloat4 aA[2][2], aB[2][2];
    unsigned o0 = 0, o1 = SLOT, o2 = 2 * SLOT;

    // prologue: stage halves 0,1; A-pair for period 0. vmcnt(8): both stages
    // retired, pair (8 loads) in flight. Body's first barrier completes sync.
    STAGE(o0, 0);
    STAGE(o1, 1);
    SCHED_FENCE();
    PAIR(aA, 0);
    SCHED_FENCE();
    VMW(8);

#pragma unroll 1
    for (int it = 0; it < 15; ++it) {      // 15 bodies x 4 steps = halves 0..59
        const int j = 4 * it;
        // step j (even): compute half j from o0
        BARL();
        STAGE(o2, j + 2);
        SCHED_FENCE();
        PAIR(aB, 2 * it + 1);
        SCHED_FENCE();
        VMW(12);
        SCHED_FENCE();
        COMP(aA[0][0], aA[1][0], o0);
        SCHED_FENCE();
        // step j+1 (odd): half j+1 from o1
        BARL();
        STAGE(o0, j + 3);
        SCHED_FENCE();
        VMW(12);
        SCHED_FENCE();
        COMP(aA[0][1], aA[1][1], o1);
        SCHED_FENCE();
        // step j+2 (even): half j+2 from o2
        BARL();
        STAGE(o1, j + 4);
        SCHED_FENCE();
        PAIR(aA, 2 * it + 2);
        SCHED_FENCE();
        VMW(12);
        SCHED_FENCE();
        COMP(aB[0][0], aB[1][0], o2);
        SCHED_FENCE();
        // step j+3 (odd): half j+3 from o0
        BARL();
        STAGE(o2, j + 5);
        SCHED_FENCE();
        VMW(12);
        SCHED_FENCE();
        COMP(aB[0][1], aB[1][1], o0);
        SCHED_FENCE();
        // ring advance: 4 steps = +1 (mod 3)
        const unsigned tr = o0; o0 = o1; o1 = o2; o2 = tr;
    }

    // drain: steps 60..63 (offsets rotated 15x = back to start roles)
    BARL();
    STAGE(o2, 62);
    SCHED_FENCE();
    PAIR(aB, 31);
    SCHED_FENCE();
    VMW(12);
    SCHED_FENCE();
    COMP(aA[0][0], aA[1][0], o0);          // half 60
    SCHED_FENCE();
    BARL();
    STAGE(o0, 63);
    SCHED_FENCE();
    VMW(12);
    SCHED_FENCE();
    COMP(aA[0][1], aA[1][1], o1);          // half 61
    SCHED_FENCE();
    BARL();
    VMW(0);
    SCHED_FENCE();
    COMP(aB[0][0], aB[1][0], o2);          // half 62
    SCHED_FENCE();
    BARL();
    COMP(aB[0][1], aB[1][1], o0);          // half 63

#undef VMW
#undef BARL

    // butterfly-reduce 32 (r,c) partials; lane v=r*16+c (v<32) keeps value v.
    float o = 0.f;
#pragma unroll
    for (int r = 0; r < 2; ++r) {
#pragma unroll
        for (int c = 0; c < 16; ++c) {
            float s = acc[r][c];
            s += __shfl_xor(s, 1);  s += __shfl_xor(s, 2);  s += __shfl_xor(s, 4);
            s += __shfl_xor(s, 8);  s += __shfl_xor(s, 16); s += __shfl_xor(s, 32);
            o = (r * 16 + c == lane) ? s : o;
        }
    }
    if (lane < 32) {
        if (HASBIAS) o += bias[lane & 15];
        if (RELU) o = fmaxf(o, 0.f);
        out[row0 * 16 + lane] = o;
    }
}

// ---------------- K3: hw = h1 @ W2  ([N,16]@[16,16]) ----------------
__global__ __launch_bounds__(256) void k3_hw(const float* __restrict__ h1,
                                             const float* __restrict__ W2,
                                             float* __restrict__ hw) {
    __shared__ float w2s[256];
    w2s[threadIdx.x] = W2[threadIdx.x];
    __syncthreads();
    const size_t r = (size_t)blockIdx.x * 256 + threadIdx.x;
    float h[16];
#pragma unroll
    for (int q = 0; q < 4; ++q) {
        float4 v = *reinterpret_cast<const float4*>(h1 + r * 16 + q * 4);
        h[q * 4 + 0] = v.x; h[q * 4 + 1] = v.y; h[q * 4 + 2] = v.z; h[q * 4 + 3] = v.w;
    }
#pragma unroll
    for (int q = 0; q < 4; ++q) {
        float4 o;
#pragma unroll
        for (int j = 0; j < 4; ++j) {
            const int c = q * 4 + j;
            float s = 0.f;
#pragma unroll
            for (int k = 0; k < 16; ++k) s += h[k] * w2s[k * 16 + c];
            (&o.x)[j] = s;
        }
        *reinterpret_cast<float4*>(hw + r * 16 + q * 4) = o;
    }
}

// ---------------- K5: out = softmax(g) @ Wd + bd ----------------
__global__ __launch_bounds__(256) void k5_head(const float* __restrict__ g,
                                               const float* __restrict__ Wd,
                                               const float* __restrict__ bd,
                                               float* __restrict__ out) {
    const size_t r = (size_t)blockIdx.x * 256 + threadIdx.x;
    float v[16];
#pragma unroll
    for (int q = 0; q < 4; ++q) {
        float4 t = *reinterpret_cast<const float4*>(g + r * 16 + q * 4);
        v[q * 4 + 0] = t.x; v[q * 4 + 1] = t.y; v[q * 4 + 2] = t.z; v[q * 4 + 3] = t.w;
    }
    float m = v[0];
#pragma unroll
    for (int c = 1; c < 16; ++c) m = fmaxf(m, v[c]);
    float se = 0.f, sd = 0.f;
#pragma unroll
    for (int c = 0; c < 16; ++c) {
        const float e = expf(v[c] - m);
        se += e;
        sd += e * Wd[c];
    }
    out[r] = sd / se + bd[0];
}

extern "C" void kernel_launch(void* const* d_in, const int* in_sizes, int n_in,
                              void* d_out, int out_size, void* d_ws, size_t ws_size,
                              hipStream_t stream) {
    const float* x  = (const float*)d_in[0];
    const float* A  = (const float*)d_in[1];
    const float* W1 = (const float*)d_in[2];
    const float* b1 = (const float*)d_in[3];
    const float* W2 = (const float*)d_in[4];
    const float* b2 = (const float*)d_in[5];
    const float* Wd = (const float*)d_in[6];
    const float* bd = (const float*)d_in[7];
    float* out = (float*)d_out;

    float* ws = (float*)d_ws;
    float* xw = ws;                        // [N,16] 1 MB
    float* h1 = ws + 1 * N_NODES * 16;     // [N,16] 1 MB
    float* hw = ws + 2 * N_NODES * 16;     // [N,16] 1 MB
    float* gl = ws + 3 * N_NODES * 16;     // [N,16] 1 MB

    // xw = x @ W1
    k_rowagg<FDIM, 0, 0><<<N_NODES / 16, 256, 0, stream>>>(x, W1, b1, xw);
    // h1 = relu(A @ xw + b1)   (2 KB-visit kernel)
    k_rowagg2<1, 1><<<N_NODES / 8, 256, 0, stream>>>(A, xw, b1, h1);
    // hw = h1 @ W2
    k3_hw<<<N_NODES / 256, 256, 0, stream>>>(h1, W2, hw);
    // gl = A @ hw + b2
    k_rowagg2<0, 1><<<N_NODES / 8, 256, 0, stream>>>(A, hw, b2, gl);
    // out = softmax(gl) @ Wd + bd
    k5_head<<<N_NODES / 256, 256, 0, stream>>>(gl, Wd, bd, out);
}

// Round 11
// 453.823 us; speedup vs baseline: 1.2392x; 1.2392x over previous
//
#include <hip/hip_runtime.h>
#include <hip/hip_bf16.h>

#define N_NODES 16384
#define FDIM 512

typedef __attribute__((address_space(1))) const void gvoid_t;
typedef __attribute__((address_space(3))) void lvoid_t;
typedef float vfloat4 __attribute__((ext_vector_type(4)));

#define SCHED_FENCE() __builtin_amdgcn_sched_barrier(0)

// ---------------- pipelined row-aggregation GEMM ----------------
// r9 structure, UNCHANGED in the K-loop (461 us total; the proven shape):
// 4 waves/block, 4 rows/wave (RPW=4 is the LDS floor: LDS-reads/wave/tile are
// fixed at 16 KB, so RPW<4 doubles LDS-read per A-byte -> LDS-bound, the r7/r10
// regressions), KT=256 double-buffered LDS, glds w16 staging, XOR-swizzled tile,
// counted vmcnt(4) + raw s_barrier, nt A-loads.
// NEW: fused epilogues. FUSE=0: plain write (k1). FUSE=1: xW2 16x16 matmul via
// 16 shfl+FMA -> writes hw (kills k3). FUSE=2: 16-lane-group softmax dot Wd +bd
// -> writes out scalar per row (kills k5).
template <int KTOT, int RELU, int HASBIAS, int FUSE>
__global__ __launch_bounds__(256, 2)
void k_rowagg(const float* __restrict__ A,
              const float* __restrict__ V,
              const float* __restrict__ bias,
              float* __restrict__ out,
              const float* __restrict__ w2,
              const float* __restrict__ wd,
              const float* __restrict__ bdp) {
    constexpr int KT = 256;
    constexpr int NT = KTOT / KT;
    constexpr int TB = KT * 16 * 4;
    __shared__ char lv[2 * TB];

    const int tid = threadIdx.x;
    const int lane = tid & 63;
    const int w = tid >> 6;
    const size_t row0 = (size_t)blockIdx.x * 16 + (size_t)w * 4;

    int sw_src[4];
#pragma unroll
    for (int s = 0; s < 4; ++s) {
        const int D = s * 4096 + tid * 16;
        sw_src[s] = (D ^ (((D >> 8) & 7) << 4)) >> 2;
    }

    unsigned zoff = 0;

    auto STAGE = [&](int halfoff, int t) {
        const float* vt = V + (size_t)t * (KT * 16);
#pragma unroll
        for (int s = 0; s < 4; ++s) {
            __builtin_amdgcn_global_load_lds(
                (gvoid_t*)(const void*)(vt + sw_src[s]),
                (lvoid_t*)(void*)(lv + zoff + halfoff + s * 4096 + tid * 16),
                16, 0, 0);
        }
    };

    auto LOADA = [&](vfloat4 (&a)[4], int t) {
#pragma unroll
        for (int r = 0; r < 4; ++r)
            a[r] = __builtin_nontemporal_load(
                reinterpret_cast<const vfloat4*>(
                    A + (row0 + r) * (size_t)KTOT + (size_t)t * KT + lane * 4));
    };

    float acc[4][16];
#pragma unroll
    for (int r = 0; r < 4; ++r)
#pragma unroll
        for (int c = 0; c < 16; ++c) acc[r][c] = 0.f;

    auto COMPUTE = [&](const vfloat4 (&a)[4], unsigned roff) {
#pragma unroll
        for (int kk = 0; kk < 4; ++kk) {
            vfloat4 vv[4];
#pragma unroll
            for (int cc = 0; cc < 4; ++cc) {
                const unsigned B = (unsigned)lane * 256u + ((unsigned)kk << 6) +
                                   ((unsigned)cc << 4);
                const unsigned P = B ^ (((unsigned)lane & 7u) << 4);
                vv[cc] = *reinterpret_cast<const vfloat4*>(lv + roff + P);
            }
#pragma unroll
            for (int cc = 0; cc < 4; ++cc) {
#pragma unroll
                for (int r = 0; r < 4; ++r) {
                    const float ak = a[r][kk];
                    acc[r][cc * 4 + 0] += ak * vv[cc][0];
                    acc[r][cc * 4 + 1] += ak * vv[cc][1];
                    acc[r][cc * 4 + 2] += ak * vv[cc][2];
                    acc[r][cc * 4 + 3] += ak * vv[cc][3];
                }
            }
        }
    };

    vfloat4 a0[4], a1[4];

    STAGE(0, 0);
    SCHED_FENCE();
    LOADA(a0, 0);
    SCHED_FENCE();
    asm volatile("s_waitcnt vmcnt(4)" ::: "memory");
    __builtin_amdgcn_s_barrier();
    asm volatile("" : "+v"(zoff));
    SCHED_FENCE();

#pragma unroll 1
    for (int t = 0; t < NT; t += 2) {
        STAGE(TB, t + 1);
        SCHED_FENCE();
        LOADA(a1, t + 1);
        SCHED_FENCE();
        COMPUTE(a0, zoff + 0);
        SCHED_FENCE();
        asm volatile("s_waitcnt vmcnt(4)" ::: "memory");
        __builtin_amdgcn_s_barrier();
        asm volatile("" : "+v"(zoff));
        SCHED_FENCE();

        if (t + 2 < NT) {
            STAGE(0, t + 2);
            SCHED_FENCE();
            LOADA(a0, t + 2);
            SCHED_FENCE();
            COMPUTE(a1, zoff + TB);
            SCHED_FENCE();
            asm volatile("s_waitcnt vmcnt(4)" ::: "memory");
            __builtin_amdgcn_s_barrier();
            asm volatile("" : "+v"(zoff));
            SCHED_FENCE();
        } else {
            COMPUTE(a1, zoff + TB);
        }
    }

    // butterfly-reduce the 64 (r,c) partials; lane v=r*16+c keeps value v.
    float o = 0.f;
#pragma unroll
    for (int r = 0; r < 4; ++r) {
#pragma unroll
        for (int c = 0; c < 16; ++c) {
            float s = acc[r][c];
            s += __shfl_xor(s, 1);  s += __shfl_xor(s, 2);  s += __shfl_xor(s, 4);
            s += __shfl_xor(s, 8);  s += __shfl_xor(s, 16); s += __shfl_xor(s, 32);
            o = (r * 16 + c == lane) ? s : o;
        }
    }
    if (HASBIAS) o += bias[lane & 15];
    if (RELU) o = fmaxf(o, 0.f);

    if (FUSE == 0) {
        out[row0 * 16 + lane] = o;
    } else if (FUSE == 1) {
        // hw[row][c] = sum_k h[row][k] * W2[k][c]; h[row][k] lives in lane (lane&48)|k
        const int c = lane & 15;
        float s = 0.f;
#pragma unroll
        for (int k = 0; k < 16; ++k) {
            const float hk = __shfl(o, (lane & 48) + k);
            s += hk * w2[k * 16 + c];
        }
        out[row0 * 16 + lane] = s;
    } else {
        // softmax over the 16-lane class group, dot Wd, + bd -> one scalar per row
        const int c = lane & 15;
        float m = o;
        m = fmaxf(m, __shfl_xor(m, 1));
        m = fmaxf(m, __shfl_xor(m, 2));
        m = fmaxf(m, __shfl_xor(m, 4));
        m = fmaxf(m, __shfl_xor(m, 8));
        const float e = expf(o - m);
        float se = e, sd = e * wd[c];
        se += __shfl_xor(se, 1); sd += __shfl_xor(sd, 1);
        se += __shfl_xor(se, 2); sd += __shfl_xor(sd, 2);
        se += __shfl_xor(se, 4); sd += __shfl_xor(sd, 4);
        se += __shfl_xor(se, 8); sd += __shfl_xor(sd, 8);
        if (c == 0) out[row0 + (lane >> 4)] = sd / se + bdp[0];
    }
}

extern "C" void kernel_launch(void* const* d_in, const int* in_sizes, int n_in,
                              void* d_out, int out_size, void* d_ws, size_t ws_size,
                              hipStream_t stream) {
    const float* x  = (const float*)d_in[0];
    const float* A  = (const float*)d_in[1];
    const float* W1 = (const float*)d_in[2];
    const float* b1 = (const float*)d_in[3];
    const float* W2 = (const float*)d_in[4];
    const float* b2 = (const float*)d_in[5];
    const float* Wd = (const float*)d_in[6];
    const float* bd = (const float*)d_in[7];
    float* out = (float*)d_out;

    float* ws = (float*)d_ws;
    float* xw = ws;                        // [N,16] 1 MB
    float* hw = ws + 1 * N_NODES * 16;     // [N,16] 1 MB

    // xw = x @ W1
    k_rowagg<FDIM, 0, 0, 0><<<N_NODES / 16, 256, 0, stream>>>(
        x, W1, b1, xw, nullptr, nullptr, nullptr);
    // hw = relu(A @ xw + b1) @ W2    (pass 1, fused k3)
    k_rowagg<N_NODES, 1, 1, 1><<<N_NODES / 16, 256, 0, stream>>>(
        A, xw, b1, hw, W2, nullptr, nullptr);
    // out = softmax(A @ hw + b2) @ Wd + bd    (pass 2, fused k5)
    k_rowagg<N_NODES, 0, 1, 2><<<N_NODES / 16, 256, 0, stream>>>(
        A, hw, b2, out, nullptr, Wd, bd);
}